// Round 15
// baseline (1954.685 us; speedup 1.0000x reference)
//
#include <hip/hip_runtime.h>
#include <hip/hip_fp16.h>

#define DT 5e-5f
#define SPRING_Y 30000.0f
#define DASHPOT 100.0f
// exp(-DT * DRAG_DAMPING) = exp(-5e-5)
#define DRAG 0.9999500012499792f

// xv layout: xv[2*i] = position, xv[2*i+1] = velocity (w unused).
// 32B per vertex, 32B-aligned -> both halves in ONE 64B line.
// adj entry: 4 BYTES: (neighbor_idx:17) << 15 | (fp16(1/rest) & 0x7fff).
// Stride layout: vertex v's entries at adj[v*64 .. v*64+deg[v]).
// Fill is SLICE-OWNED (R13-proven): 8 vertex slices (~3.2MB of adj each, one
// XCD-L2 worth); block b handles spring chunk b>>3, writes only slice b&7.
// R14: each fill lane processes TWO springs via one int4+float2 load.
// substep: 8 lanes/vertex; lane pairs fetch each 64B xv line cooperatively
// (R10-proven). Last substep also writes the packed (NV,3) output directly.

// ---------- one-time (per launch) build ----------

__global__ void init_k(const float* __restrict__ x0, float4* __restrict__ xv,
                       int* __restrict__ deg, int nv) {
    int i = blockIdx.x * blockDim.x + threadIdx.x;
    if (i < nv) {
        xv[2 * i]     = make_float4(x0[3 * i], x0[3 * i + 1], x0[3 * i + 2], 0.0f);
        xv[2 * i + 1] = make_float4(0.0f, 0.0f, 0.0f, 0.0f);
        deg[i] = 0;
    }
}

__global__ void fill_sliced_k(const int4* __restrict__ springs2,
                              const float2* __restrict__ rest2,
                              int* __restrict__ deg, unsigned* __restrict__ adj,
                              int ns2, int nv, int S) {
    // ns2 = ns/2 spring-pairs; each lane handles 2 springs.
    int b = blockIdx.x;
    int slice = b & 7;
    int s = (b >> 3) * blockDim.x + threadIdx.x;
    if (s >= ns2) return;

    int lo = (int)(((long long)slice * nv) >> 3);
    int hi = (int)(((long long)(slice + 1) * nv) >> 3);

    int4 pp = springs2[s];          // springs 2s: (pp.x,pp.y), 2s+1: (pp.z,pp.w)
    float2 rr = rest2[s];

    unsigned h0 = __half_as_ushort(__float2half(1.0f / rr.x)) & 0x7fffu;
    unsigned h1 = __half_as_ushort(__float2half(1.0f / rr.y)) & 0x7fffu;

    if (pp.x >= lo && pp.x < hi) {
        int a = atomicAdd(&deg[pp.x], 1);
        adj[pp.x * S + a] = ((unsigned)pp.y << 15) | h0;
    }
    if (pp.y >= lo && pp.y < hi) {
        int a = atomicAdd(&deg[pp.y], 1);
        adj[pp.y * S + a] = ((unsigned)pp.x << 15) | h0;
    }
    if (pp.z >= lo && pp.z < hi) {
        int a = atomicAdd(&deg[pp.z], 1);
        adj[pp.z * S + a] = ((unsigned)pp.w << 15) | h1;
    }
    if (pp.w >= lo && pp.w < hi) {
        int a = atomicAdd(&deg[pp.w], 1);
        adj[pp.w * S + a] = ((unsigned)pp.z << 15) | h1;
    }
}

// ---------- fused per-substep kernel ----------

__global__ void __launch_bounds__(256) substep_k(
        const float4* __restrict__ xvin, float4* __restrict__ xvout,
        const unsigned* __restrict__ adj, const int* __restrict__ deg,
        const float* __restrict__ mass, int nv, int S,
        float* __restrict__ out) {
    int gid = blockIdx.x * blockDim.x + threadIdx.x;
    int vid = gid >> 3;
    int sub = gid & 7;
    if (vid >= nv) return;

    float4 xa = xvin[2 * vid];
    float4 va = xvin[2 * vid + 1];
    int s0 = vid * S;
    int s1 = s0 + deg[vid];
    int last = s1 - 1;                 // segment-clamp target (valid when deg>0)
    int par = sub & 1;                 // lane parity within its pair

    float fx = 0.0f, fy = 0.0f, fz = 0.0f;
    int pf = s0 + (sub & ~1);          // pair's first entry index
    int j  = pf + par;                 // this lane's own entry index

    if (pf < s1) {                     // pair-uniform: both pair lanes iterate together
        for (;;) {
            unsigned e = adj[min(j, last)];     // own entry (clamped dup if tail)
            float msk = (j <= last) ? 1.0f : 0.0f;
            int n = (int)(e >> 15);
            float invr = __uint_as_float(((e & 0x7fffu) << 13) + (112u << 23));

            int pn = __shfl_xor(n, 1);          // partner's neighbor
            int nA = par ? pn : n;              // even lane's entry
            int nB = par ? n : pn;              // odd lane's entry

            // instr1: pair fetches A's 64B line (two 16B halves, one line-touch)
            float4 t1 = xvin[2 * nA + par];         // even: xA, odd: vA
            // instr2: pair fetches B's line
            float4 t2 = xvin[2 * nB + (1 - par)];   // even: vB, odd: xB

            // reassemble own entry's (x,v)
            float4 xb, u;
            xb.x = par ? t2.x : t1.x;
            xb.y = par ? t2.y : t1.y;
            xb.z = par ? t2.z : t1.z;
            u.x  = par ? t1.x : t2.x;   // the half this lane must SEND
            u.y  = par ? t1.y : t2.y;
            u.z  = par ? t1.z : t2.z;
            float4 vb;
            vb.x = __shfl_xor(u.x, 1);
            vb.y = __shfl_xor(u.y, 1);
            vb.z = __shfl_xor(u.z, 1);

            float dx = xb.x - xa.x, dy = xb.y - xa.y, dz = xb.z - xa.z;
            float len = sqrtf(dx * dx + dy * dy + dz * dz);
            float il = 1.0f / len;              // clamped dups are valid: len > 0
            float ddx = dx * il, ddy = dy * il, ddz = dz * il;
            float vrel = (vb.x - va.x) * ddx + (vb.y - va.y) * ddy + (vb.z - va.z) * ddz;
            float coef = (SPRING_Y * (len * invr - 1.0f) + DASHPOT * vrel) * msk;
            fx += coef * ddx;
            fy += coef * ddy;
            fz += coef * ddz;

            pf += 8;
            if (pf >= s1) break;
            j += 8;
        }
    }

    // reduce across the 8 lanes of this vertex (xor stays within the group)
    fx += __shfl_xor(fx, 1);
    fx += __shfl_xor(fx, 2);
    fx += __shfl_xor(fx, 4);
    fy += __shfl_xor(fy, 1);
    fy += __shfl_xor(fy, 2);
    fy += __shfl_xor(fy, 4);
    fz += __shfl_xor(fz, 1);
    fz += __shfl_xor(fz, 2);
    fz += __shfl_xor(fz, 4);

    if (sub == 0) {
        float m = mass[vid];
        fz += m * (-9.8f);
        float invm = 1.0f / m;

        va.x = (va.x + DT * fx * invm) * DRAG;
        va.y = (va.y + DT * fy * invm) * DRAG;
        va.z = (va.z + DT * fz * invm) * DRAG;

        xa.x += DT * va.x;
        xa.y += DT * va.y;
        xa.z += DT * va.z;
        xa.z = fmaxf(xa.z, 0.0f);
        if (xa.z == 0.0f) va.z = 0.0f;

        xvout[2 * vid]     = xa;
        xvout[2 * vid + 1] = va;

        if (out) {                     // final substep: emit packed (NV,3) output
            out[3 * vid + 0] = xa.x;
            out[3 * vid + 1] = xa.y;
            out[3 * vid + 2] = xa.z;
        }
    }
}

extern "C" void kernel_launch(void* const* d_in, const int* in_sizes, int n_in,
                              void* d_out, int out_size, void* d_ws, size_t ws_size,
                              hipStream_t stream) {
    const float* x0      = (const float*)d_in[0];   // (NV,3) fp32
    const int*   springs = (const int*)d_in[1];     // (NS,2) int32
    const float* rest    = (const float*)d_in[2];   // (NS,)  fp32
    const float* mass    = (const float*)d_in[3];   // (NV,)  fp32

    const int ns = in_sizes[2];        // 1,000,000
    const int nv = in_sizes[3];        // 100,000
    const int nb = (nv + 255) / 256;
    const int ns2 = ns >> 1;           // spring pairs (ns is even)

    // workspace layout
    char* ws = (char*)d_ws;
    size_t o = 0;
    float4* xva   = (float4*)(ws + o); o += (size_t)nv * 32;   // x,v interleaved
    float4* xvb   = (float4*)(ws + o); o += (size_t)nv * 32;
    int* deg      = (int*)(ws + o);    o += (((size_t)nv * 4 + 15) & ~15ull);
    unsigned* adj = (unsigned*)(ws + o);                        // nv*64*4B = 25.6 MB

    const int STRIDE = 64;

    dim3 blk(256);
    dim3 vgrid(nb);
    dim3 fgrid(8 * ((ns2 + 255) / 256));          // 8 slices x spring-pair chunks
    dim3 subgrid(((size_t)nv * 8 + 255) / 256);   // 8 lanes per vertex

    // one-time build (replayed every call; amortized over 100 substeps)
    init_k<<<vgrid, blk, 0, stream>>>(x0, xva, deg, nv);
    fill_sliced_k<<<fgrid, blk, 0, stream>>>((const int4*)springs, (const float2*)rest,
                                             deg, adj, ns2, nv, STRIDE);

    const int NSUB = 100;
    float4* xi = xva;
    float4* xo = xvb;
    for (int t = 0; t < NSUB; ++t) {
        float* out = (t == NSUB - 1) ? (float*)d_out : nullptr;
        substep_k<<<subgrid, blk, 0, stream>>>(xi, xo, adj, deg, mass, nv, STRIDE, out);
        float4* tmp = xi; xi = xo; xo = tmp;
    }
}